// Round 2
// baseline (100.271 us; speedup 1.0000x reference)
//
#include <hip/hip_runtime.h>
#include <hip/hip_bf16.h>
#include <math.h>

// Shapes
#define QL 32768
#define DD 1024
#define NTOK 64

using short8   = __attribute__((ext_vector_type(8))) short;
using f32x4    = __attribute__((ext_vector_type(4))) float;
using float4v  = __attribute__((ext_vector_type(4))) float;
using ushort4v = __attribute__((ext_vector_type(4))) unsigned short;
using ushort8v = __attribute__((ext_vector_type(8))) unsigned short;

__device__ __forceinline__ unsigned short f2bf(float f) {
    unsigned int u = __float_as_uint(f);
    unsigned int r = (u + 0x7FFFu + ((u >> 16) & 1u)) >> 16;
    return (unsigned short)r;
}

// ---------------------------------------------------------------------------
// Transpose-convert: dst[c][r] = bf16(src[r][c]).  src is R x C fp32 row-major,
// dst is C x R bf16 row-major. grid = (R/64)*(C/64) blocks, 256 threads.
// ---------------------------------------------------------------------------
__global__ __launch_bounds__(256) void transpose_cvt_kernel(
        const float* __restrict__ src, unsigned short* __restrict__ dst,
        int R, int C) {
    __shared__ float tile[64][65];
    const int TC  = C >> 6;
    const int r0  = (blockIdx.x / TC) << 6;
    const int c0  = (blockIdx.x % TC) << 6;
    const int tid = threadIdx.x;
#pragma unroll
    for (int i = 0; i < 16; ++i) {
        const int lin = tid + 256 * i;       // 0..4095
        const int row = lin >> 6, col = lin & 63;
        tile[row][col] = src[(size_t)(r0 + row) * C + c0 + col];
    }
    __syncthreads();
#pragma unroll
    for (int i = 0; i < 16; ++i) {
        const int lin = tid + 256 * i;
        const int row = lin >> 6, col = lin & 63;
        // dst[c0+row][r0+col] = src[r0+col][c0+row] = tile[col][row]
        dst[(size_t)(c0 + row) * R + r0 + col] = f2bf(tile[col][row]);
    }
}

// ---------------------------------------------------------------------------
// Kp = Pk @ Wq  (Kp[t][d] = sum_e Pk[t][e] * Wq[e][d]) via bf16 MFMA.
// A = Pk (fp32, converted in-register), B[k=e][n=d] = WqT[d][e] (bf16).
// grid 16 blocks (64 d-cols each), 256 threads = 4 waves (16 token-rows each).
// ---------------------------------------------------------------------------
__global__ __launch_bounds__(256) void kp_mfma_kernel(
        const float* __restrict__ Pk, const unsigned short* __restrict__ WqT,
        unsigned short* __restrict__ Kp) {
    const int tid = threadIdx.x;
    const int w   = tid >> 6;
    const int l   = tid & 63;
    const int lhi = l >> 4;
    const int llo = l & 15;
    const int N0  = blockIdx.x * 64;

    f32x4 acc[4];
#pragma unroll
    for (int ct = 0; ct < 4; ++ct) acc[ct] = (f32x4){0.f, 0.f, 0.f, 0.f};

    for (int kb = 0; kb < 32; ++kb) {
        const int k0 = kb * 32 + lhi * 8;
        float4v p0 = *(const float4v*)(Pk + (size_t)(w * 16 + llo) * DD + k0);
        float4v p1 = *(const float4v*)(Pk + (size_t)(w * 16 + llo) * DD + k0 + 4);
        short8 a;
        a[0] = (short)f2bf(p0.x); a[1] = (short)f2bf(p0.y);
        a[2] = (short)f2bf(p0.z); a[3] = (short)f2bf(p0.w);
        a[4] = (short)f2bf(p1.x); a[5] = (short)f2bf(p1.y);
        a[6] = (short)f2bf(p1.z); a[7] = (short)f2bf(p1.w);
#pragma unroll
        for (int ct = 0; ct < 4; ++ct) {
            short8 b = *(const short8*)(WqT + (size_t)(N0 + ct * 16 + llo) * DD + k0);
            acc[ct] = __builtin_amdgcn_mfma_f32_16x16x32_bf16(a, b, acc[ct], 0, 0, 0);
        }
    }
#pragma unroll
    for (int ct = 0; ct < 4; ++ct) {
#pragma unroll
        for (int j = 0; j < 4; ++j) {
            const int t = w * 16 + lhi * 4 + j;      // D row = token
            const int d = N0 + ct * 16 + llo;        // D col = d
            Kp[(size_t)t * DD + d] = f2bf(acc[ct][j]);
        }
    }
}

// ---------------------------------------------------------------------------
// Fused: s = x @ Kp^T -> row l2-norm * 8 -> exact GELU -> y = s' @ Pv
// grid 512 blocks (64 rows each), 256 threads = 4 waves; wave owns 16 rows.
// ---------------------------------------------------------------------------
__global__ __launch_bounds__(256, 2) void fused_kernel(
        const float* __restrict__ x, const unsigned short* __restrict__ Kp,
        const unsigned short* __restrict__ PvT, float* __restrict__ out) {
    // sA = x tile bf16 [64][128] swizzled (16KB); sB = Kp tile bf16 [64][128] (16KB);
    // sS = s' bf16 [64][64] swizzled (8KB)
    __shared__ __align__(16) unsigned char smem[16384 + 16384 + 8192];
    unsigned char* sA = smem;
    unsigned char* sB = smem + 16384;
    unsigned char* sS = smem + 32768;

    const int tid = threadIdx.x;
    const int w   = tid >> 6;
    const int l   = tid & 63;
    const int lhi = l >> 4;    // 0..3
    const int llo = l & 15;    // 0..15
    const int R0  = blockIdx.x * 64;

    f32x4 acc[4];
#pragma unroll
    for (int ct = 0; ct < 4; ++ct) acc[ct] = (f32x4){0.f, 0.f, 0.f, 0.f};

    // ---- Phase A: GEMM1, K loop of 8 x BK=128 ----
    for (int kk = 0; kk < 8; ++kk) {
        const int kbase = kk * 128;
        // global -> regs
        float4v xv[8];
#pragma unroll
        for (int i = 0; i < 8; ++i) {
            const int lin = tid + 256 * i;          // 0..2047
            const int row = lin >> 5;               // 0..63
            const int c4  = (lin & 31) << 2;        // element offset 0..124
            xv[i] = *(const float4v*)(x + (size_t)(R0 + row) * DD + kbase + c4);
        }
        ushort8v kv[4];
#pragma unroll
        for (int i = 0; i < 4; ++i) {
            const int lin  = tid + 256 * i;         // 0..1023
            const int t    = lin >> 4;              // 0..63   (16 chunks per row!)
            const int part = lin & 15;              // 0..15 (8-elem = 16B units)
            kv[i] = *(const ushort8v*)(Kp + (size_t)t * DD + kbase + part * 8);
        }
        __syncthreads();  // previous iter's LDS reads done
        // regs -> LDS (bf16, XOR-swizzled: byte ^= (row&7)<<4)
#pragma unroll
        for (int i = 0; i < 8; ++i) {
            const int lin = tid + 256 * i;
            const int row = lin >> 5;
            const int c4  = (lin & 31) << 2;
            ushort4v bv;
            bv.x = f2bf(xv[i].x); bv.y = f2bf(xv[i].y);
            bv.z = f2bf(xv[i].z); bv.w = f2bf(xv[i].w);
            const int off = (row * 256 + c4 * 2) ^ ((row & 7) << 4);
            *(ushort4v*)(sA + off) = bv;
        }
#pragma unroll
        for (int i = 0; i < 4; ++i) {
            const int lin  = tid + 256 * i;
            const int t    = lin >> 4;
            const int part = lin & 15;
            const int off = (t * 256 + part * 16) ^ ((t & 7) << 4);
            *(ushort8v*)(sB + off) = kv[i];
        }
        __syncthreads();
        // MFMA: 4 k-substeps x 4 col-tiles
#pragma unroll
        for (int ks = 0; ks < 4; ++ks) {
            const int ko = ks * 64 + lhi * 16;      // byte col offset
            const int arow = w * 16 + llo;
            short8 a = *(const short8*)(sA + ((arow * 256 + ko) ^ ((arow & 7) << 4)));
#pragma unroll
            for (int ct = 0; ct < 4; ++ct) {
                const int brow = ct * 16 + llo;
                short8 bfr = *(const short8*)(sB + ((brow * 256 + ko) ^ ((brow & 7) << 4)));
                acc[ct] = __builtin_amdgcn_mfma_f32_16x16x32_bf16(a, bfr, acc[ct], 0, 0, 0);
            }
        }
    }

    // ---- Phase B: row l2-norm (over 64 tokens) * 8, exact GELU, bf16 -> sS ----
    // acc[ct][j] = s[row = w*16 + lhi*4 + j][t = ct*16 + llo]
    float scale[4];
#pragma unroll
    for (int j = 0; j < 4; ++j) {
        float s2 = 0.f;
#pragma unroll
        for (int ct = 0; ct < 4; ++ct) s2 += acc[ct][j] * acc[ct][j];
        s2 += __shfl_xor(s2, 1);
        s2 += __shfl_xor(s2, 2);
        s2 += __shfl_xor(s2, 4);
        s2 += __shfl_xor(s2, 8);
        scale[j] = 8.0f / sqrtf(s2);
    }
#pragma unroll
    for (int ct = 0; ct < 4; ++ct) {
#pragma unroll
        for (int j = 0; j < 4; ++j) {
            const float v = acc[ct][j] * scale[j];
            const float g = 0.5f * v * (1.0f + erff(v * 0.70710678118654752f));
            const int lr = w * 16 + lhi * 4 + j;
            const int t  = ct * 16 + llo;
            const int off = (lr * 128 + t * 2) ^ ((lr & 7) << 4);
            *(unsigned short*)(sS + off) = f2bf(g);
        }
    }
    __syncthreads();

    // ---- Phase C: GEMM2  y = s'(64x64) @ Pv(64x1024), B frags from L2 (PvT) ----
    short8 a0, a1;
    {
        const int arow = w * 16 + llo;
        a0 = *(const short8*)(sS + ((arow * 128 + 0 * 64 + lhi * 16) ^ ((arow & 7) << 4)));
        a1 = *(const short8*)(sS + ((arow * 128 + 1 * 64 + lhi * 16) ^ ((arow & 7) << 4)));
    }
    for (int nc = 0; nc < 16; ++nc) {
        const int N0 = nc * 64;
        f32x4 acc2[4];
#pragma unroll
        for (int ct = 0; ct < 4; ++ct) acc2[ct] = (f32x4){0.f, 0.f, 0.f, 0.f};
#pragma unroll
        for (int ct = 0; ct < 4; ++ct) {
            const unsigned short* bp0 = PvT + (size_t)(N0 + ct * 16 + llo) * 64 + lhi * 8;
            short8 b0 = *(const short8*)bp0;
            short8 b1 = *(const short8*)(bp0 + 32);
            acc2[ct] = __builtin_amdgcn_mfma_f32_16x16x32_bf16(a0, b0, acc2[ct], 0, 0, 0);
            acc2[ct] = __builtin_amdgcn_mfma_f32_16x16x32_bf16(a1, b1, acc2[ct], 0, 0, 0);
        }
#pragma unroll
        for (int ct = 0; ct < 4; ++ct) {
#pragma unroll
            for (int j = 0; j < 4; ++j) {
                const int r = R0 + w * 16 + lhi * 4 + j;
                const int c = N0 + ct * 16 + llo;
                out[(size_t)r * DD + c] = acc2[ct][j];
            }
        }
    }
}

// ---------------------------------------------------------------------------
extern "C" void kernel_launch(void* const* d_in, const int* in_sizes, int n_in,
                              void* d_out, int out_size, void* d_ws, size_t ws_size,
                              hipStream_t stream) {
    (void)in_sizes; (void)n_in; (void)out_size; (void)ws_size;
    const float* x  = (const float*)d_in[0];
    const float* Wq = (const float*)d_in[1];
    const float* Pk = (const float*)d_in[2];
    const float* Pv = (const float*)d_in[3];
    float* out = (float*)d_out;

    // ws layout (2.25 MB total):
    //   WqT bf16 [1024][1024] @ 0        (2 MB)
    //   Kp  bf16 [64][1024]   @ 2 MB     (128 KB)
    //   PvT bf16 [1024][64]   @ 2 MB+128K (128 KB)
    unsigned short* WqT = (unsigned short*)d_ws;
    unsigned short* Kp  = (unsigned short*)((char*)d_ws + 2097152);
    unsigned short* PvT = (unsigned short*)((char*)d_ws + 2097152 + 131072);

    transpose_cvt_kernel<<<256, 256, 0, stream>>>(Wq, WqT, 1024, 1024);
    transpose_cvt_kernel<<<16, 256, 0, stream>>>(Pv, PvT, 64, 1024);
    kp_mfma_kernel<<<16, 256, 0, stream>>>(Pk, WqT, Kp);
    fused_kernel<<<512, 256, 0, stream>>>(x, Kp, PvT, out);
}